// Round 1
// baseline (1370.429 us; speedup 1.0000x reference)
//
#include <hip/hip_runtime.h>

// SegmentCSR sum: out[s, :] = sum_{r in [indptr[s], indptr[s+1])} x[r, :]
// x: [TOTAL, 128] fp32 (rows of a segment are CONTIGUOUS in memory)
// indptr: [N_SEG+1] int32
// out: [N_SEG, 128] fp32
//
// Strategy: one wave (64 lanes) per segment. D=128 floats = 32 float4.
// Lane L: float4-column c = L&31, row-phase rh = L>>5 (two rows in flight
// per wave iteration -> each global_load_dwordx4 covers 1 KiB contiguous).
// Combine the two half-wave partials with __shfl_down(.,32); lanes 0..31
// store the output row. Memory-bound: ~1.07 GB read + 33.5 MB write.

#define NSEG 65536
#define D4   32   // 128 floats = 32 float4

__global__ __launch_bounds__(256) void segcsr_kernel(
    const float4* __restrict__ x,      // [TOTAL * 32] float4
    const int*    __restrict__ indptr, // [NSEG + 1]
    float4*       __restrict__ out)    // [NSEG * 32] float4
{
    const int seg  = (blockIdx.x << 2) + (threadIdx.x >> 6); // 4 waves/block
    const int lane = threadIdx.x & 63;
    const int c    = lane & 31;   // float4 column
    const int rh   = lane >> 5;   // row phase: 0 or 1

    const int begin = indptr[seg];
    const int end   = indptr[seg + 1];

    float ax = 0.f, ay = 0.f, az = 0.f, aw = 0.f;
    for (int r = begin + rh; r < end; r += 2) {
        const float4 v = x[(long long)r * D4 + c];
        ax += v.x; ay += v.y; az += v.z; aw += v.w;
    }

    // Fold the two half-wave partials (same column, rows offset by 1).
    ax += __shfl_down(ax, 32);
    ay += __shfl_down(ay, 32);
    az += __shfl_down(az, 32);
    aw += __shfl_down(aw, 32);

    if (rh == 0) {
        float4 o; o.x = ax; o.y = ay; o.z = az; o.w = aw;
        out[(long long)seg * D4 + c] = o;
    }
}

extern "C" void kernel_launch(void* const* d_in, const int* in_sizes, int n_in,
                              void* d_out, int out_size, void* d_ws, size_t ws_size,
                              hipStream_t stream) {
    const float4* x      = (const float4*)d_in[0];
    const int*    indptr = (const int*)d_in[1];
    float4*       out    = (float4*)d_out;

    // 4 segments (waves) per 256-thread block.
    dim3 grid(NSEG / 4), block(256);
    segcsr_kernel<<<grid, block, 0, stream>>>(x, indptr, out);
}